// Round 5
// baseline (199.232 us; speedup 1.0000x reference)
//
#include <hip/hip_runtime.h>

// Problem constants (from reference)
#define NUM_BLOCKS 1024
#define BLOCK_SIZE 128
#define NUM_HEADS 8
#define HEAD_DIM 128
#define NUM_TOKENS 8192
#define ROW_FLOATS (NUM_HEADS * HEAD_DIM)        // 1024 floats per slot row
#define ROW_F4 (ROW_FLOATS / 4)                  // 256 f32x4 per slot row
#define TOTAL_ROWS (NUM_BLOCKS * BLOCK_SIZE)     // 131072 slot rows

typedef float f32x4 __attribute__((ext_vector_type(4)));  // native vec for nontemporal builtins

// Kernel 1: init slot->token map to -1.
__global__ void kv_map_init(int* __restrict__ map) {
    const int i = blockIdx.x * blockDim.x + threadIdx.x;
    map[i] = -1;
}

// Kernel 2: scatter token ids into the map (destination slots are unique).
__global__ void kv_map_scatter(const int* __restrict__ bidx,
                               const int* __restrict__ boff,
                               int* __restrict__ map) {
    const int t = blockIdx.x * blockDim.x + threadIdx.x;
    if (t < NUM_TOKENS) {
        map[bidx[t] * BLOCK_SIZE + boff[t]] = t;
    }
}

// Kernel 3: output-driven fused copy. Two rows per wave, all 8 loads issued
// before any store (128 B in flight per lane) — no loop-carried serialization.
__global__ void kv_fused_copy(const f32x4* __restrict__ inp,
                              const f32x4* __restrict__ cache,
                              const int* __restrict__ map,
                              f32x4* __restrict__ out) {
    const int wid  = (blockIdx.x * blockDim.x + threadIdx.x) >> 6;  // wave id
    const int lane = threadIdx.x & 63;
    const int row0 = wid * 2;
    const int row1 = row0 + 1;
    const int tok0 = map[row0];                              // wave-uniform
    const int tok1 = map[row1];
    const f32x4* __restrict__ src0 =
        (tok0 >= 0) ? (inp + (size_t)tok0 * ROW_F4)
                    : (cache + (size_t)row0 * ROW_F4);
    const f32x4* __restrict__ src1 =
        (tok1 >= 0) ? (inp + (size_t)tok1 * ROW_F4)
                    : (cache + (size_t)row1 * ROW_F4);
    f32x4 v[8];
#pragma unroll
    for (int i = 0; i < 4; ++i)
        v[i] = __builtin_nontemporal_load(&src0[lane + 64 * i]);
#pragma unroll
    for (int i = 0; i < 4; ++i)
        v[4 + i] = __builtin_nontemporal_load(&src1[lane + 64 * i]);
    f32x4* __restrict__ dst0 = out + (size_t)row0 * ROW_F4;
    f32x4* __restrict__ dst1 = out + (size_t)row1 * ROW_F4;
#pragma unroll
    for (int i = 0; i < 4; ++i)
        __builtin_nontemporal_store(v[i], &dst0[lane + 64 * i]);
#pragma unroll
    for (int i = 0; i < 4; ++i)
        __builtin_nontemporal_store(v[4 + i], &dst1[lane + 64 * i]);
}

extern "C" void kernel_launch(void* const* d_in, const int* in_sizes, int n_in,
                              void* d_out, int out_size, void* d_ws, size_t ws_size,
                              hipStream_t stream) {
    const float* input = (const float*)d_in[0];        // [8192, 8, 128] fp32
    const float* cache = (const float*)d_in[1];        // [1024, 128, 8, 128] fp32
    const int* block_indices = (const int*)d_in[2];    // [8192] int
    const int* block_offset = (const int*)d_in[3];     // [8192] int
    float* out = (float*)d_out;                        // [1024, 128, 8, 128] fp32
    int* map = (int*)d_ws;                             // 131072 ints (512 KiB)

    kv_map_init<<<TOTAL_ROWS / 256, 256, 0, stream>>>(map);
    kv_map_scatter<<<NUM_TOKENS / 256, 256, 0, stream>>>(block_indices,
                                                         block_offset, map);
    // 2 rows per wave: 65536 waves = 16384 blocks of 256 threads
    kv_fused_copy<<<TOTAL_ROWS / 8, 256, 0, stream>>>(
        (const f32x4*)input, (const f32x4*)cache, map, (f32x4*)out);
}

// Round 6
// 180.735 us; speedup vs baseline: 1.1023x; 1.1023x over previous
//
#include <hip/hip_runtime.h>

// Problem constants (from reference)
#define NUM_BLOCKS 1024
#define BLOCK_SIZE 128
#define NUM_HEADS 8
#define HEAD_DIM 128
#define NUM_TOKENS 8192
#define ROW_FLOATS (NUM_HEADS * HEAD_DIM)        // 1024 floats per slot row
#define ROW_F4 (ROW_FLOATS / 4)                  // 256 f32x4 per slot row
#define TOTAL_ROWS (NUM_BLOCKS * BLOCK_SIZE)     // 131072 slot rows

typedef float f32x4 __attribute__((ext_vector_type(4)));  // native vec for nontemporal builtins

// Kernel 1: init slot->token map to -1.
__global__ void kv_map_init(int* __restrict__ map) {
    const int i = blockIdx.x * blockDim.x + threadIdx.x;
    map[i] = -1;
}

// Kernel 2: scatter token ids into the map (destination slots are unique).
__global__ void kv_map_scatter(const int* __restrict__ bidx,
                               const int* __restrict__ boff,
                               int* __restrict__ map) {
    const int t = blockIdx.x * blockDim.x + threadIdx.x;
    if (t < NUM_TOKENS) {
        map[bidx[t] * BLOCK_SIZE + boff[t]] = t;
    }
}

// Kernel 3: output-driven fused copy. One wave per slot row; 4 rows per block.
// Each row is 1024 floats = 256 f32x4; each of the 64 lanes moves 4 f32x4.
// One row per wave (max TLP) measured fastest: 179.6 us. Batching 2 rows/wave
// (R5) or grid-striding 8 rows/wave (R4) both regressed ~10%.
__global__ void kv_fused_copy(const f32x4* __restrict__ inp,
                              const f32x4* __restrict__ cache,
                              const int* __restrict__ map,
                              f32x4* __restrict__ out) {
    const int row  = blockIdx.x * 4 + (threadIdx.x >> 6);   // slot row
    const int lane = threadIdx.x & 63;
    const int tok  = map[row];                               // wave-uniform
    const f32x4* __restrict__ src =
        (tok >= 0) ? (inp + (size_t)tok * ROW_F4)
                   : (cache + (size_t)row * ROW_F4);
    f32x4* __restrict__ dst = out + (size_t)row * ROW_F4;
#pragma unroll
    for (int i = 0; i < 4; ++i) {
        f32x4 v = __builtin_nontemporal_load(&src[lane + 64 * i]);
        __builtin_nontemporal_store(v, &dst[lane + 64 * i]);
    }
}

extern "C" void kernel_launch(void* const* d_in, const int* in_sizes, int n_in,
                              void* d_out, int out_size, void* d_ws, size_t ws_size,
                              hipStream_t stream) {
    const float* input = (const float*)d_in[0];        // [8192, 8, 128] fp32
    const float* cache = (const float*)d_in[1];        // [1024, 128, 8, 128] fp32
    const int* block_indices = (const int*)d_in[2];    // [8192] int
    const int* block_offset = (const int*)d_in[3];     // [8192] int
    float* out = (float*)d_out;                        // [1024, 128, 8, 128] fp32
    int* map = (int*)d_ws;                             // 131072 ints (512 KiB)

    kv_map_init<<<TOTAL_ROWS / 256, 256, 0, stream>>>(map);
    kv_map_scatter<<<NUM_TOKENS / 256, 256, 0, stream>>>(block_indices,
                                                         block_offset, map);
    kv_fused_copy<<<TOTAL_ROWS / 4, 256, 0, stream>>>(
        (const f32x4*)input, (const f32x4*)cache, map, (f32x4*)out);
}